// Round 5
// baseline (131.169 us; speedup 1.0000x reference)
//
#include <hip/hip_runtime.h>
#include <hip/hip_bf16.h>

#define Bb 8
#define Tt 32
#define Ss 256
#define Dd 1024
// 2/ln(2): tanh(z) = 1 - 2*rcp(exp2(z*SCALE)+1)
#define SCALE 2.885390081777927f

typedef short short8 __attribute__((ext_vector_type(8)));
typedef float floatx4 __attribute__((ext_vector_type(4)));

__device__ __forceinline__ unsigned short bf16b(float x) {
    __hip_bfloat16 h = __float2bfloat16(x);
    return *(unsigned short*)&h;
}

__device__ __forceinline__ float dot4(float4 a, float4 b) {
    return a.x * b.x + a.y * b.y + a.z * b.z + a.w * b.w;
}

// Factored sigmoid term: e = eq*em = exp2(SCALE*(q+m));  acc += w * rcp(e+1)
// 3 VALU + 1 trans per element.
__device__ __forceinline__ float sig2(float eqv, float emv, float w, float acc) {
    float e = eqv * emv;
    return fmaf(w, __builtin_amdgcn_rcpf(e + 1.f), acc);
}

// K1 — section order chosen so the latency-bound serial cumsum chains launch
// FIRST and overlap with the streaming cast instead of trailing it:
//     blocks [0,64):    prefix-mean -> bf16 (serial 32-step chains)
//     blocks [64,128):  w_colsum partials
//     blocks [128,1152): cast W_q1/W_q2 to bf16 (float4-vectorized)
__global__ __launch_bounds__(256) void prep_kernel(
        const float* __restrict__ src1, const float* __restrict__ src2,
        const float* __restrict__ m1, const float* __restrict__ m2,
        const float* __restrict__ W1, const float* __restrict__ W2,
        const float* __restrict__ Wv,
        unsigned short* __restrict__ W1b, unsigned short* __restrict__ W2b,
        unsigned short* __restrict__ s1b, unsigned short* __restrict__ s2b,
        float* __restrict__ part) {
    const int blk = blockIdx.x, tid = threadIdx.x;
    if (blk < 64) {
        const int idx = blk * 256 + tid;            // 16384 chains
        const int srcsel = idx >> 13;
        const int bd = idx & 8191;
        const int b = bd >> 10, d = bd & 1023;
        const float* sp = srcsel ? src2 : src1;
        const float* mp = srcsel ? m2 : m1;
        unsigned short* op = srcsel ? s2b : s1b;
        float a = 0.f;
        for (int t = 0; t < Tt; t++) {
            a += sp[(size_t)(b * Tt + t) * Dd + d];
            float inv = __builtin_amdgcn_rcpf((float)(t + 1));
            op[(size_t)(b * Tt + t) * Dd + d] = bf16b(a * inv * mp[b * Tt + t]);
        }
    } else if (blk < 128) {
        const int bb = blk - 64;
        const int db = bb & 3, jc = bb >> 2;
        const int d = db * 256 + tid;
        float a = 0.f;
        const int j0 = jc * 64;
        for (int j = 0; j < 64; j++)
            a += Wv[(size_t)(j0 + j) * Dd + d];
        part[jc * Dd + d] = a;
    } else {
        const int idx = (blk - 128) * 256 + tid;    // 262144 float4 groups = 1M elems
        float4 a = ((const float4*)W1)[idx];
        float4 b = ((const float4*)W2)[idx];
        ushort4 oa = { bf16b(a.x), bf16b(a.y), bf16b(a.z), bf16b(a.w) };
        ushort4 ob = { bf16b(b.x), bf16b(b.y), bf16b(b.z), bf16b(b.w) };
        ((ushort4*)W1b)[idx] = oa;
        ((ushort4*)W2b)[idx] = ob;
    }
}

// K2 — 256-thread blocks:
//   blocks [0,128): GEMM. Block = 64m x 32n; wave w owns m-tile m0=mblk*64+w*16.
//     All 4 waves load IDENTICAL B addresses (same n0) on the same CU -> L1
//     absorbs 3/4 of B traffic (64->16 MB L2 reads).
//   blocks [128,132): wsum final reduce (1024 d, one thread each)
//   blocks [132,644): pa/pb rows — wave per (b,s); co-resident latency filler.
__global__ __launch_bounds__(256) void gemm_kernel(
        const unsigned short* __restrict__ s1b, const unsigned short* __restrict__ s2b,
        const unsigned short* __restrict__ W1b, const unsigned short* __restrict__ W2b,
        const float* __restrict__ bq1, const float* __restrict__ bq2,
        const float* __restrict__ part, const float* __restrict__ mem,
        const float* __restrict__ Wc,
        float* __restrict__ qp, float* __restrict__ wsum,
        float* __restrict__ pab) {
    const int blk = blockIdx.x;
    const int tid = threadIdx.x;
    const int wave = tid >> 6;
    const int lane = tid & 63;
    if (blk >= 132) {                        // pa/pb rows
        const int bs = (blk - 132) * 4 + wave;   // 0..2047
        const float4* mrow = (const float4*)mem + (size_t)bs * 256;
        const float4* Wc4 = (const float4*)Wc;
        float a0 = 0.f, a1 = 0.f, b0 = 0.f, b1 = 0.f;
        #pragma unroll
        for (int j = 0; j < 4; j++) {
            const int idx = j * 64 + lane;
            float4 m_ = mrow[idx];
            a0 += dot4(m_, Wc4[idx]);
            b0 += dot4(m_, Wc4[256 + idx]);
            a1 += dot4(m_, Wc4[512 + idx]);
            b1 += dot4(m_, Wc4[768 + idx]);
        }
        #pragma unroll
        for (int o = 32; o > 0; o >>= 1) {
            a0 += __shfl_xor(a0, o);
            a1 += __shfl_xor(a1, o);
            b0 += __shfl_xor(b0, o);
            b1 += __shfl_xor(b1, o);
        }
        if (lane == 0) {
            float4 r = { a0, a1, b0, b1 };
            ((float4*)pab)[bs] = r;
        }
        return;
    }
    if (blk >= 128) {                        // wsum final
        const int d = (blk - 128) * 256 + tid;
        float a = 0.f;
        #pragma unroll
        for (int jc = 0; jc < 16; jc++)
            a += part[jc * Dd + d];
        wsum[d] = a;
        return;
    }
    const int mblk = blk & 3, nblk = blk >> 2;
    const int m0 = mblk * 64 + wave * 16;    // M = 256, 4 m-tiles per block
    const int n0 = nblk * 32;                // N = 1024, two 16-wide n-tiles
    const int lm = lane & 15;
    const int quad = lane >> 4;

    floatx4 acc0 = {0.f, 0.f, 0.f, 0.f};
    floatx4 acc1 = {0.f, 0.f, 0.f, 0.f};
    const unsigned short* a1p = s1b + (size_t)(m0 + lm) * Dd;
    const unsigned short* a2p = s2b + (size_t)(m0 + lm) * Dd;
    const unsigned short* b1a = W1b + (size_t)(n0 + lm) * Dd;
    const unsigned short* b1b = W1b + (size_t)(n0 + 16 + lm) * Dd;
    const unsigned short* b2a = W2b + (size_t)(n0 + lm) * Dd;
    const unsigned short* b2b = W2b + (size_t)(n0 + 16 + lm) * Dd;

    #pragma unroll 2
    for (int k0 = 0; k0 < Dd; k0 += 32) {
        const int off = k0 + quad * 8;
        short8 a1 = *(const short8*)(a1p + off);
        short8 a2 = *(const short8*)(a2p + off);
        short8 vb1a = *(const short8*)(b1a + off);
        short8 vb2a = *(const short8*)(b2a + off);
        short8 vb1b = *(const short8*)(b1b + off);
        short8 vb2b = *(const short8*)(b2b + off);
        acc0 = __builtin_amdgcn_mfma_f32_16x16x32_bf16(a1, vb1a, acc0, 0, 0, 0);
        acc1 = __builtin_amdgcn_mfma_f32_16x16x32_bf16(a1, vb1b, acc1, 0, 0, 0);
        acc0 = __builtin_amdgcn_mfma_f32_16x16x32_bf16(a2, vb2a, acc0, 0, 0, 0);
        acc1 = __builtin_amdgcn_mfma_f32_16x16x32_bf16(a2, vb2b, acc1, 0, 0, 0);
    }

    const int na = n0 + lm, nb = n0 + 16 + lm;
    const float biasa = bq1[na] + bq2[na];
    const float biasb = bq1[nb] + bq2[nb];
    #pragma unroll
    for (int r = 0; r < 4; r++) {
        const int m = m0 + quad * 4 + r;   // C/D: col=lane&15, row=quad*4+reg
        qp[(size_t)m * Dd + na] = __builtin_amdgcn_exp2f(SCALE * (acc0[r] + biasa));
        qp[(size_t)m * Dd + nb] = __builtin_amdgcn_exp2f(SCALE * (acc1[r] + biasb));
    }
}

// K3 — block = (b, 4-s tile), 8 waves cover all 32 t (4 each).
// em = exp2(SCALE*mem) staged into LDS ONCE per (b,s-tile) (was twice).
// Inner element: e = eq*em; acc += w*rcp(e+1)  -> 3 VALU + 1 trans.
__global__ __launch_bounds__(512) void out_kernel(
        const float* __restrict__ eq, const float* __restrict__ mem,
        const float* __restrict__ wsum, const float* __restrict__ pab,
        const float* __restrict__ bc, float* __restrict__ out) {
    __shared__ float em_s[4 * 1024];
    const int tid = threadIdx.x;
    const int wave = tid >> 6;
    const int lane = tid & 63;
    const int blk = blockIdx.x;                  // 0..511
    const int sq = blk & 63, b = blk >> 6;
    const int s0 = sq * 4;
    const int t0 = wave * 4;
    const int bs0 = b * Ss + s0;

    // cooperative stage: 1024 float4 total, 512 threads x 2
    {
        const float4* mem4 = (const float4*)mem;
        float4* es = (float4*)em_s;
        #pragma unroll
        for (int k = 0; k < 2; k++) {
            const int i2 = tid + 512 * k;
            const int row = i2 >> 8, col = i2 & 255;
            float4 m_ = mem4[(size_t)(bs0 + row) * 256 + col];
            float4 e4 = { __builtin_amdgcn_exp2f(SCALE * m_.x),
                          __builtin_amdgcn_exp2f(SCALE * m_.y),
                          __builtin_amdgcn_exp2f(SCALE * m_.z),
                          __builtin_amdgcn_exp2f(SCALE * m_.w) };
            es[i2] = e4;
        }
    }

    const float4* q4 = (const float4*)eq;
    const float4* wsum4 = (const float4*)wsum;

    float4 wv[4];
    float Wl = 0.f;
    #pragma unroll
    for (int j = 0; j < 4; j++) {
        wv[j] = wsum4[j * 64 + lane];
        Wl += wv[j].x + wv[j].y + wv[j].z + wv[j].w;
    }
    #pragma unroll
    for (int o = 32; o > 0; o >>= 1) Wl += __shfl_xor(Wl, o);

    const float bc0 = bc[0], bc1 = bc[1];
    float C0[4], C1[4], D0[4], D1[4];
    #pragma unroll
    for (int si = 0; si < 4; si++) {
        float4 pv = ((const float4*)pab)[bs0 + si];   // {pa0,pa1,pb0,pb1}
        C0[si] = pv.x + Wl * pv.z + bc0;
        C1[si] = pv.y + Wl * pv.w + bc1;
        D0[si] = 2.f * pv.z;
        D1[si] = 2.f * pv.w;
    }

    float p[4][4];
    #pragma unroll
    for (int ti = 0; ti < 4; ti++)
        #pragma unroll
        for (int si = 0; si < 4; si++) p[ti][si] = 0.f;

    __syncthreads();

    #pragma unroll
    for (int j = 0; j < 4; j++) {
        const int idx = j * 64 + lane;
        float4 emj[4], qj[4];
        #pragma unroll
        for (int si = 0; si < 4; si++)
            emj[si] = ((const float4*)em_s)[si * 256 + idx];
        #pragma unroll
        for (int ti = 0; ti < 4; ti++)
            qj[ti] = q4[(size_t)(b * Tt + t0 + ti) * 256 + idx];
        const float4 w_ = wv[j];
        #pragma unroll
        for (int ti = 0; ti < 4; ti++) {
            #pragma unroll
            for (int si = 0; si < 4; si++) {
                float acc = p[ti][si];
                acc = sig2(qj[ti].x, emj[si].x, w_.x, acc);
                acc = sig2(qj[ti].y, emj[si].y, w_.y, acc);
                acc = sig2(qj[ti].z, emj[si].z, w_.z, acc);
                acc = sig2(qj[ti].w, emj[si].w, w_.w, acc);
                p[ti][si] = acc;
            }
        }
    }

    #pragma unroll
    for (int ti = 0; ti < 4; ti++)
        #pragma unroll
        for (int si = 0; si < 4; si++) {
            float v = p[ti][si];
            #pragma unroll
            for (int o = 32; o > 0; o >>= 1) v += __shfl_xor(v, o);
            p[ti][si] = v;
        }

    if (lane == 0) {
        #pragma unroll
        for (int ti = 0; ti < 4; ti++) {
            const size_t rowo = ((size_t)(b * Tt + t0 + ti) * Ss + s0) * 2;
            #pragma unroll
            for (int si = 0; si < 4; si++) {
                float2 o2 = { C0[si] - D0[si] * p[ti][si],
                              C1[si] - D1[si] * p[ti][si] };
                *(float2*)(out + rowo + si * 2) = o2;
            }
        }
    }
}

extern "C" void kernel_launch(void* const* d_in, const int* in_sizes, int n_in,
                              void* d_out, int out_size, void* d_ws, size_t ws_size,
                              hipStream_t stream) {
    const float* src1 = (const float*)d_in[0];
    const float* src2 = (const float*)d_in[1];
    const float* mem  = (const float*)d_in[2];
    const float* m1   = (const float*)d_in[3];
    const float* m2   = (const float*)d_in[4];
    const float* Wq1  = (const float*)d_in[5];
    const float* bq1  = (const float*)d_in[6];
    const float* Wq2  = (const float*)d_in[7];
    const float* bq2  = (const float*)d_in[8];
    const float* Wc   = (const float*)d_in[9];
    const float* bc   = (const float*)d_in[10];
    const float* Wv   = (const float*)d_in[11];
    float* out = (float*)d_out;

    char* ws = (char*)d_ws;
    unsigned short* s1b = (unsigned short*)(ws);                 // 512 KB
    unsigned short* s2b = (unsigned short*)(ws + (512u << 10));  // 512 KB
    unsigned short* W1b = (unsigned short*)(ws + (1u << 20));    // 2 MB
    unsigned short* W2b = (unsigned short*)(ws + (3u << 20));    // 2 MB
    float* qp   = (float*)(ws + (5u << 20));                     // 1 MB (eq)
    float* wsum = (float*)(ws + (6u << 20));                     // 4 KB
    float* part = (float*)(ws + (6u << 20) + 4096);              // 64 KB
    float* pab  = (float*)(ws + (6u << 20) + 4096 + 65536);      // 32 KB

    prep_kernel<<<1152, 256, 0, stream>>>(src1, src2, m1, m2, Wq1, Wq2, Wv,
                                          W1b, W2b, s1b, s2b, part);
    gemm_kernel<<<644, 256, 0, stream>>>(s1b, s2b, W1b, W2b, bq1, bq2, part,
                                         mem, Wc, qp, wsum, pab);
    out_kernel<<<512, 512, 0, stream>>>(qp, mem, wsum, pab, bc, out);
}

// Round 6
// 118.490 us; speedup vs baseline: 1.1070x; 1.1070x over previous
//
#include <hip/hip_runtime.h>
#include <hip/hip_bf16.h>

#define Bb 8
#define Tt 32
#define Ss 256
#define Dd 1024
// 2/ln(2): tanh(z) = 1 - 2*rcp(exp2(z*SCALE)+1)
#define SCALE 2.885390081777927f

typedef short short8 __attribute__((ext_vector_type(8)));
typedef float floatx4 __attribute__((ext_vector_type(4)));

__device__ __forceinline__ unsigned short bf16b(float x) {
    __hip_bfloat16 h = __float2bfloat16(x);
    return *(unsigned short*)&h;
}

__device__ __forceinline__ float dot4(float4 a, float4 b) {
    return a.x * b.x + a.y * b.y + a.z * b.z + a.w * b.w;
}

// Factored sigmoid term: e = eq*em = exp2(SCALE*(q+m));  acc += w * rcp(e+1)
// 3 VALU + 1 trans per element (vs 3 VALU + 2 trans unfactored).
__device__ __forceinline__ float sig2(float eqv, float emv, float w, float acc) {
    float e = eqv * emv;
    return fmaf(w, __builtin_amdgcn_rcpf(e + 1.f), acc);
}

// K1: blocks [0,1024): cast W_q1/W_q2 to bf16 (float4-vectorized)
//     blocks [1024,1088): w_colsum partials
//     blocks [1088,1152): prefix-mean -> bf16
//     blocks [1152,1664): pab rows + em = exp2(SCALE*mem) (one wave per (b,s);
//                         mem row loaded ONCE, reused for both outputs)
__global__ __launch_bounds__(256) void prep_kernel(
        const float* __restrict__ src1, const float* __restrict__ src2,
        const float* __restrict__ m1, const float* __restrict__ m2,
        const float* __restrict__ W1, const float* __restrict__ W2,
        const float* __restrict__ Wv, const float* __restrict__ mem,
        const float* __restrict__ Wc,
        unsigned short* __restrict__ W1b, unsigned short* __restrict__ W2b,
        unsigned short* __restrict__ s1b, unsigned short* __restrict__ s2b,
        float* __restrict__ part, float* __restrict__ pab,
        float* __restrict__ em) {
    const int blk = blockIdx.x, tid = threadIdx.x;
    if (blk < 1024) {
        const int idx = blk * 256 + tid;            // 262144 float4 groups = 1M elems
        float4 a = ((const float4*)W1)[idx];
        float4 b = ((const float4*)W2)[idx];
        ushort4 oa = { bf16b(a.x), bf16b(a.y), bf16b(a.z), bf16b(a.w) };
        ushort4 ob = { bf16b(b.x), bf16b(b.y), bf16b(b.z), bf16b(b.w) };
        ((ushort4*)W1b)[idx] = oa;
        ((ushort4*)W2b)[idx] = ob;
    } else if (blk < 1088) {
        const int bb = blk - 1024;
        const int db = bb & 3, jc = bb >> 2;
        const int d = db * 256 + tid;
        float a = 0.f;
        const int j0 = jc * 64;
        for (int j = 0; j < 64; j++)
            a += Wv[(size_t)(j0 + j) * Dd + d];
        part[jc * Dd + d] = a;
    } else if (blk < 1152) {
        const int idx = (blk - 1088) * 256 + tid;   // 16384 chains
        const int srcsel = idx >> 13;
        const int bd = idx & 8191;
        const int b = bd >> 10, d = bd & 1023;
        const float* sp = srcsel ? src2 : src1;
        const float* mp = srcsel ? m2 : m1;
        unsigned short* op = srcsel ? s2b : s1b;
        float a = 0.f;
        for (int t = 0; t < Tt; t++) {
            a += sp[(size_t)(b * Tt + t) * Dd + d];
            float inv = __builtin_amdgcn_rcpf((float)(t + 1));
            op[(size_t)(b * Tt + t) * Dd + d] = bf16b(a * inv * mp[b * Tt + t]);
        }
    } else {
        // pab + em: one wave per (b,s) row — 2048 waves in 512 blocks
        const int lane = tid & 63;
        const int bs = (blk - 1152) * 4 + (tid >> 6);
        const float4* mrow = (const float4*)mem + (size_t)bs * 256;
        float4* emr = (float4*)em + (size_t)bs * 256;
        const float4* Wc4 = (const float4*)Wc;
        float a0 = 0.f, a1 = 0.f, b0 = 0.f, b1 = 0.f;
        #pragma unroll
        for (int j = 0; j < 4; j++) {
            const int idx = j * 64 + lane;
            float4 m_ = mrow[idx];
            a0 += dot4(m_, Wc4[idx]);
            b0 += dot4(m_, Wc4[256 + idx]);
            a1 += dot4(m_, Wc4[512 + idx]);
            b1 += dot4(m_, Wc4[768 + idx]);
            float4 e4 = { __builtin_amdgcn_exp2f(SCALE * m_.x),
                          __builtin_amdgcn_exp2f(SCALE * m_.y),
                          __builtin_amdgcn_exp2f(SCALE * m_.z),
                          __builtin_amdgcn_exp2f(SCALE * m_.w) };
            emr[idx] = e4;
        }
        #pragma unroll
        for (int o = 32; o > 0; o >>= 1) {
            a0 += __shfl_xor(a0, o);
            a1 += __shfl_xor(a1, o);
            b0 += __shfl_xor(b0, o);
            b1 += __shfl_xor(b1, o);
        }
        if (lane == 0) {
            float4 r = { a0, a1, b0, b1 };
            ((float4*)pab)[bs] = r;
        }
    }
}

// K2: blocks [0,512): one wave computes a 16x32 tile of
//       eq = exp2(SCALE*(s1@W1^T + s2@W2^T + b1 + b2))
//     blocks [512,528): wsum final reduce (1024 d / 64 lanes)
__global__ __launch_bounds__(64) void gemm_kernel(
        const unsigned short* __restrict__ s1b, const unsigned short* __restrict__ s2b,
        const unsigned short* __restrict__ W1b, const unsigned short* __restrict__ W2b,
        const float* __restrict__ bq1, const float* __restrict__ bq2,
        const float* __restrict__ part,
        float* __restrict__ qp, float* __restrict__ wsum) {
    const int blk = blockIdx.x;
    const int lane = threadIdx.x;
    if (blk >= 512) {                        // wsum final
        const int d = (blk - 512) * 64 + lane;
        float a = 0.f;
        #pragma unroll
        for (int jc = 0; jc < 16; jc++)
            a += part[jc * Dd + d];
        wsum[d] = a;
        return;
    }
    const int m0 = (blk & 15) * 16;       // M = 256
    const int n0 = (blk >> 4) * 32;       // N = 1024, two 16-wide n-tiles
    const int lm = lane & 15;
    const int quad = lane >> 4;

    floatx4 acc0 = {0.f, 0.f, 0.f, 0.f};
    floatx4 acc1 = {0.f, 0.f, 0.f, 0.f};
    const unsigned short* a1p = s1b + (size_t)(m0 + lm) * Dd;
    const unsigned short* a2p = s2b + (size_t)(m0 + lm) * Dd;
    const unsigned short* b1a = W1b + (size_t)(n0 + lm) * Dd;
    const unsigned short* b1b = W1b + (size_t)(n0 + 16 + lm) * Dd;
    const unsigned short* b2a = W2b + (size_t)(n0 + lm) * Dd;
    const unsigned short* b2b = W2b + (size_t)(n0 + 16 + lm) * Dd;

    #pragma unroll 2
    for (int k0 = 0; k0 < Dd; k0 += 32) {
        const int off = k0 + quad * 8;
        short8 a1 = *(const short8*)(a1p + off);
        short8 a2 = *(const short8*)(a2p + off);
        short8 vb1a = *(const short8*)(b1a + off);
        short8 vb2a = *(const short8*)(b2a + off);
        short8 vb1b = *(const short8*)(b1b + off);
        short8 vb2b = *(const short8*)(b2b + off);
        acc0 = __builtin_amdgcn_mfma_f32_16x16x32_bf16(a1, vb1a, acc0, 0, 0, 0);
        acc1 = __builtin_amdgcn_mfma_f32_16x16x32_bf16(a1, vb1b, acc1, 0, 0, 0);
        acc0 = __builtin_amdgcn_mfma_f32_16x16x32_bf16(a2, vb2a, acc0, 0, 0, 0);
        acc1 = __builtin_amdgcn_mfma_f32_16x16x32_bf16(a2, vb2b, acc1, 0, 0, 0);
    }

    const int na = n0 + lm, nb = n0 + 16 + lm;
    const float biasa = bq1[na] + bq2[na];
    const float biasb = bq1[nb] + bq2[nb];
    #pragma unroll
    for (int r = 0; r < 4; r++) {
        const int m = m0 + quad * 4 + r;   // C/D: col=lane&15, row=quad*4+reg
        qp[(size_t)m * Dd + na] = __builtin_amdgcn_exp2f(SCALE * (acc0[r] + biasa));
        qp[(size_t)m * Dd + nb] = __builtin_amdgcn_exp2f(SCALE * (acc1[r] + biasb));
    }
}

// K3: block = (b, tgroup of 16 t, 4-s tile); 4 waves each own a 4-t subtile.
// em rows (shared across the block's 4 waves) staged in LDS once.
// Inner element: e = eq*em; acc += w*rcp(e+1)  -> 3 VALU + 1 trans.
__global__ __launch_bounds__(256) void out_kernel(
        const float* __restrict__ eq, const float* __restrict__ em,
        const float* __restrict__ wsum, const float* __restrict__ pab,
        const float* __restrict__ bc, float* __restrict__ out) {
    __shared__ float em_s[4 * 1024];
    const int tid = threadIdx.x;
    const int wave = tid >> 6;
    const int lane = tid & 63;
    const int blk = blockIdx.x;                  // 0..1023
    const int sq = blk & 63, tg = (blk >> 6) & 1, b = blk >> 7;
    const int s0 = sq * 4;
    const int t0 = tg * 16 + wave * 4;
    const int bs0 = b * Ss + s0;

    // cooperative em stage: 4 rows x 4 KB = 16 KB
    {
        const float4* eg = (const float4*)em + (size_t)(bs0 + wave) * 256;
        float4* es = (float4*)em_s + wave * 256;
        #pragma unroll
        for (int k = 0; k < 4; k++)
            es[(tid & 63) + 64 * k] = eg[(tid & 63) + 64 * k];
    }

    const float4* q4 = (const float4*)eq;
    const float4* wsum4 = (const float4*)wsum;

    float4 wv[4];
    float Wl = 0.f;
    #pragma unroll
    for (int j = 0; j < 4; j++) {
        wv[j] = wsum4[j * 64 + lane];
        Wl += wv[j].x + wv[j].y + wv[j].z + wv[j].w;
    }
    #pragma unroll
    for (int o = 32; o > 0; o >>= 1) Wl += __shfl_xor(Wl, o);

    const float bc0 = bc[0], bc1 = bc[1];
    float C0[4], C1[4], D0[4], D1[4];
    #pragma unroll
    for (int si = 0; si < 4; si++) {
        float4 pv = ((const float4*)pab)[bs0 + si];   // {pa0,pa1,pb0,pb1}
        C0[si] = pv.x + Wl * pv.z + bc0;
        C1[si] = pv.y + Wl * pv.w + bc1;
        D0[si] = 2.f * pv.z;
        D1[si] = 2.f * pv.w;
    }

    float p[4][4];
    #pragma unroll
    for (int ti = 0; ti < 4; ti++)
        #pragma unroll
        for (int si = 0; si < 4; si++) p[ti][si] = 0.f;

    __syncthreads();

    #pragma unroll
    for (int j = 0; j < 4; j++) {
        const int idx = j * 64 + lane;
        float4 emj[4], qj[4];
        #pragma unroll
        for (int si = 0; si < 4; si++)
            emj[si] = ((const float4*)em_s)[si * 256 + idx];
        #pragma unroll
        for (int ti = 0; ti < 4; ti++)
            qj[ti] = q4[(size_t)(b * Tt + t0 + ti) * 256 + idx];
        const float4 w_ = wv[j];
        #pragma unroll
        for (int ti = 0; ti < 4; ti++) {
            #pragma unroll
            for (int si = 0; si < 4; si++) {
                float acc = p[ti][si];
                acc = sig2(qj[ti].x, emj[si].x, w_.x, acc);
                acc = sig2(qj[ti].y, emj[si].y, w_.y, acc);
                acc = sig2(qj[ti].z, emj[si].z, w_.z, acc);
                acc = sig2(qj[ti].w, emj[si].w, w_.w, acc);
                p[ti][si] = acc;
            }
        }
    }

    #pragma unroll
    for (int ti = 0; ti < 4; ti++)
        #pragma unroll
        for (int si = 0; si < 4; si++) {
            float v = p[ti][si];
            #pragma unroll
            for (int o = 32; o > 0; o >>= 1) v += __shfl_xor(v, o);
            p[ti][si] = v;
        }

    if (lane == 0) {
        #pragma unroll
        for (int ti = 0; ti < 4; ti++) {
            const size_t rowo = ((size_t)(b * Tt + t0 + ti) * Ss + s0) * 2;
            #pragma unroll
            for (int si = 0; si < 4; si++) {
                float2 o2 = { C0[si] - D0[si] * p[ti][si],
                              C1[si] - D1[si] * p[ti][si] };
                *(float2*)(out + rowo + si * 2) = o2;
            }
        }
    }
}

extern "C" void kernel_launch(void* const* d_in, const int* in_sizes, int n_in,
                              void* d_out, int out_size, void* d_ws, size_t ws_size,
                              hipStream_t stream) {
    const float* src1 = (const float*)d_in[0];
    const float* src2 = (const float*)d_in[1];
    const float* mem  = (const float*)d_in[2];
    const float* m1   = (const float*)d_in[3];
    const float* m2   = (const float*)d_in[4];
    const float* Wq1  = (const float*)d_in[5];
    const float* bq1  = (const float*)d_in[6];
    const float* Wq2  = (const float*)d_in[7];
    const float* bq2  = (const float*)d_in[8];
    const float* Wc   = (const float*)d_in[9];
    const float* bc   = (const float*)d_in[10];
    const float* Wv   = (const float*)d_in[11];
    float* out = (float*)d_out;

    char* ws = (char*)d_ws;
    unsigned short* s1b = (unsigned short*)(ws);                 // 512 KB
    unsigned short* s2b = (unsigned short*)(ws + (512u << 10));  // 512 KB
    unsigned short* W1b = (unsigned short*)(ws + (1u << 20));    // 2 MB
    unsigned short* W2b = (unsigned short*)(ws + (3u << 20));    // 2 MB
    float* qp   = (float*)(ws + (5u << 20));                     // 1 MB (eq)
    float* wsum = (float*)(ws + (6u << 20));                     // 4 KB
    float* part = (float*)(ws + (6u << 20) + 4096);              // 64 KB
    float* pab  = (float*)(ws + (6u << 20) + 4096 + 65536);      // 32 KB
    float* em   = (float*)(ws + (7u << 20));                     // 8 MB

    prep_kernel<<<1664, 256, 0, stream>>>(src1, src2, m1, m2, Wq1, Wq2, Wv,
                                          mem, Wc, W1b, W2b, s1b, s2b,
                                          part, pab, em);
    gemm_kernel<<<528, 64, 0, stream>>>(s1b, s2b, W1b, W2b, bq1, bq2, part,
                                        qp, wsum);
    out_kernel<<<1024, 256, 0, stream>>>(qp, em, wsum, pab, bc, out);
}